// Round 13
// baseline (260.495 us; speedup 1.0000x reference)
//
#include <hip/hip_runtime.h>
#include <hip/hip_bf16.h>

typedef _Float16 f16x8 __attribute__((ext_vector_type(8)));
typedef float f32x4 __attribute__((ext_vector_type(4)));

#define MFMA16(a, b, c) __builtin_amdgcn_mfma_f32_16x16x32_f16(a, b, c, 0, 0, 0)

__device__ __forceinline__ void load_lds16(const void* g, void* l) {
  __builtin_amdgcn_global_load_lds(
      (__attribute__((address_space(1))) void*)g,
      (__attribute__((address_space(3))) void*)l, 16, 0, 0);
}

// ============ prep kernel: cvt x, cvt ctx, 4 weight transposes, Vtg pad fill ============
// One kernel (block-range dispatch) replaces 7 launches (R11: saved ~21us of gaps).
__global__ __launch_bounds__(256) void k_prep(const float* __restrict__ x,
                                              const float* __restrict__ ctx,
                                              const float* __restrict__ Wq,
                                              const float* __restrict__ Wk,
                                              const float* __restrict__ Wv,
                                              const float* __restrict__ Wo,
                                              _Float16* __restrict__ xh,
                                              _Float16* __restrict__ ctxh,
                                              _Float16* __restrict__ Wqt,
                                              _Float16* __restrict__ Wkt,
                                              _Float16* __restrict__ Wvt,
                                              _Float16* __restrict__ Wot,
                                              _Float16* __restrict__ Vtg) {
  __shared__ float tile[64][65];
  const int b = blockIdx.x, t = threadIdx.x;

  if (b < 4096) {  // ---- cvt x: 33554432 f32 -> f16, 8/thread/iter
    for (int i = b * 256 + t; i < 4194304; i += 4096 * 256) {
      const float4* p = (const float4*)(x + (size_t)i * 8);
      float4 a = p[0], c = p[1];
      f16x8 v = {(_Float16)a.x, (_Float16)a.y, (_Float16)a.z, (_Float16)a.w,
                 (_Float16)c.x, (_Float16)c.y, (_Float16)c.z, (_Float16)c.w};
      *(f16x8*)(xh + (size_t)i * 8) = v;
    }
    return;
  }
  if (b < 4327) {  // ---- cvt ctx: 473088 f32 (231*256*8 exact)
    int i = (b - 4096) * 256 + t;
    const float4* p = (const float4*)(ctx + (size_t)i * 8);
    float4 a = p[0], c = p[1];
    f16x8 v = {(_Float16)a.x, (_Float16)a.y, (_Float16)a.z, (_Float16)a.w,
               (_Float16)c.x, (_Float16)c.y, (_Float16)c.z, (_Float16)c.w};
    *(f16x8*)(ctxh + (size_t)i * 8) = v;
    return;
  }
  if (b >= 5223) {  // ---- zero Vtg pad region (512 blocks * 256 * 16B = 2MB exact)
    int i = (b - 5223) * 256 + t;
    ((f16x8*)Vtg)[i] = f16x8{};
    return;
  }
  // ---- weight transpose+convert: in[K][N] f32 -> out[N][K] f16, 64x64 tiles
  const float* tin;
  _Float16* tout;
  int TK, TN, i;
  if (b < 4583)      { tin = Wq; tout = Wqt; TK = 1024; TN = 1024; i = b - 4327; }
  else if (b < 4775) { tin = Wk; tout = Wkt; TK = 768;  TN = 1024; i = b - 4583; }
  else if (b < 4967) { tin = Wv; tout = Wvt; TK = 768;  TN = 1024; i = b - 4775; }
  else               { tin = Wo; tout = Wot; TK = 1024; TN = 1024; i = b - 4967; }
  int n0 = (i & 15) * 64, k0 = (i >> 4) * 64;
  {
    int nn = t & 63, kb = t >> 6;
#pragma unroll
    for (int s = 0; s < 16; ++s) {
      int kk = kb + s * 4;
      tile[kk][nn] = tin[(size_t)(k0 + kk) * TN + n0 + nn];
    }
  }
  __syncthreads();
  {
    int kk = t & 63, nb = t >> 6;
#pragma unroll
    for (int s = 0; s < 16; ++s) {
      int nn = nb + s * 4;
      tout[(size_t)(n0 + nn) * TK + k0 + kk] = (_Float16)tile[kk][nn];
    }
  }
}

// ---------------- K/V projection: ctxh[616][768] @ W^T -> heads ----------------
__global__ __launch_bounds__(64) void k_kvproj(const _Float16* __restrict__ ctxh,
                                               const _Float16* __restrict__ Wkt,
                                               const _Float16* __restrict__ Wvt,
                                               _Float16* __restrict__ Kg,
                                               _Float16* __restrict__ Vtg) {
  int mt = blockIdx.x, nt = blockIdx.y;
  int lane = threadIdx.x;
  int l15 = lane & 15, lhi = lane >> 4;
  int arow = mt * 16 + l15;
  if (arow > 615) arow = 615;  // clamp; masked at write
  const _Float16* ap = ctxh + (size_t)arow * 768 + lhi * 8;
  const _Float16* kp = Wkt + (size_t)(nt * 16 + l15) * 768 + lhi * 8;
  const _Float16* vp = Wvt + (size_t)(nt * 16 + l15) * 768 + lhi * 8;
  f32x4 ak = {0.f, 0.f, 0.f, 0.f}, av = {0.f, 0.f, 0.f, 0.f};
#pragma unroll 4
  for (int ks = 0; ks < 24; ++ks) {
    f16x8 a = *(const f16x8*)(ap + ks * 32);
    f16x8 bk = *(const f16x8*)(kp + ks * 32);
    f16x8 bv = *(const f16x8*)(vp + ks * 32);
    ak = MFMA16(a, bk, ak);
    av = MFMA16(a, bv, av);
  }
  int n = nt * 16 + l15, h = n >> 6, d = n & 63;
#pragma unroll
  for (int j = 0; j < 4; ++j) {
    int gm = mt * 16 + lhi * 4 + j;
    if (gm < 616) {
      int b = gm / 77, m = gm - b * 77;
      Kg[((size_t)(b * 16 + h) * 77 + m) * 64 + d] = (_Float16)ak[j];
      Vtg[((size_t)(b * 16 + h) * 64 + d) * 128 + m] = (_Float16)av[j];
    }
  }
}

// ------------- attention: one block = one (b,h) x 256 query rows (16 waves) -------------
// R13: 256 rows/block (R12 was 128) halves K/V staging + barrier overhead again.
// LDS = 10 + 16 + 64 KB = 90 KB -> 1 block/CU = 16 waves/CU (same wave count).
__global__ __launch_bounds__(1024) void k_attn(const _Float16* __restrict__ Qh,
                                               const _Float16* __restrict__ Kg,
                                               const _Float16* __restrict__ Vtg,
                                               _Float16* __restrict__ Out) {
  __shared__ __align__(16) char Kl[80 * 128];
  __shared__ __align__(16) char Vl[64 * 256];
  __shared__ __align__(16) char Pl[16 * 16 * 256];
  int bh = blockIdx.y, b = bh >> 4, h = bh & 15;
  int t = threadIdx.x, wid = t >> 6, lane = t & 63;
  int l15 = lane & 15, lhi = lane >> 4;

  const _Float16* Kgp = Kg + (size_t)bh * (77 * 64);
  const _Float16* Vgp = Vtg + (size_t)bh * (64 * 128);

  for (int idx = t; idx < 640; idx += 1024) {
    int m = idx >> 3, c = (idx & 7) * 8;
    f16x8 v = {};
    if (m < 77) v = *(const f16x8*)(Kgp + m * 64 + c);
    *(f16x8*)(Kl + ((m * 128 + c * 2) ^ ((m & 7) << 4))) = v;
  }
  for (int idx = t; idx < 1024; idx += 1024) {
    int d = idx >> 4, c = (idx & 15) * 8;
    f16x8 v = *(const f16x8*)(Vgp + d * 128 + c);
    *(f16x8*)(Vl + ((d * 256 + c * 2) ^ ((d & 7) << 4))) = v;
  }
  char* myP = Pl + wid * 4096;
#pragma unroll
  for (int i = 0; i < 4; ++i) *(f16x8*)(myP + lane * 64 + i * 16) = f16x8{};
  __syncthreads();

  int qrow = b * 4096 + blockIdx.x * 256 + wid * 16 + l15;
  const _Float16* qp = Qh + (size_t)qrow * 1024 + h * 64 + lhi * 8;
  f16x8 q0 = *(const f16x8*)qp;
  f16x8 q1 = *(const f16x8*)(qp + 32);

  float e[5][4];
  float mx[4] = {-1e30f, -1e30f, -1e30f, -1e30f};
#pragma unroll
  for (int ct = 0; ct < 5; ++ct) {
    int m = ct * 16 + l15;
    int d0b = lhi * 16;
    f16x8 k0 = *(const f16x8*)(Kl + ((m * 128 + d0b) ^ ((m & 7) << 4)));
    f16x8 k1 = *(const f16x8*)(Kl + ((m * 128 + 64 + d0b) ^ ((m & 7) << 4)));
    f32x4 acc = {0.f, 0.f, 0.f, 0.f};
    acc = MFMA16(q0, k0, acc);
    acc = MFMA16(q1, k1, acc);
    bool valid = m < 77;
#pragma unroll
    for (int j = 0; j < 4; ++j) {
      float v = valid ? acc[j] * 0.125f : -1e30f;
      e[ct][j] = v;
      mx[j] = fmaxf(mx[j], v);
    }
  }
#pragma unroll
  for (int off = 1; off < 16; off <<= 1)
#pragma unroll
    for (int j = 0; j < 4; ++j) mx[j] = fmaxf(mx[j], __shfl_xor(mx[j], off, 64));
  float sm[4] = {0.f, 0.f, 0.f, 0.f};
#pragma unroll
  for (int ct = 0; ct < 5; ++ct)
#pragma unroll
    for (int j = 0; j < 4; ++j) {
      float ev = __expf(e[ct][j] - mx[j]);
      e[ct][j] = ev;
      sm[j] += ev;
    }
#pragma unroll
  for (int off = 1; off < 16; off <<= 1)
#pragma unroll
    for (int j = 0; j < 4; ++j) sm[j] += __shfl_xor(sm[j], off, 64);
  float rs[4];
#pragma unroll
  for (int j = 0; j < 4; ++j) rs[j] = 1.0f / sm[j];

#pragma unroll
  for (int ct = 0; ct < 5; ++ct) {
    int m = ct * 16 + l15;
#pragma unroll
    for (int j = 0; j < 4; ++j) {
      int r = lhi * 4 + j;
      *(_Float16*)(myP + ((r * 256 + m * 2) ^ ((r & 7) << 4))) =
          (_Float16)(e[ct][j] * rs[j]);
    }
  }

  f32x4 o[4] = {{0.f,0.f,0.f,0.f},{0.f,0.f,0.f,0.f},{0.f,0.f,0.f,0.f},{0.f,0.f,0.f,0.f}};
#pragma unroll
  for (int ks = 0; ks < 3; ++ks) {
    int m0b = ks * 64 + lhi * 16;
    f16x8 pa = *(const f16x8*)(myP + ((l15 * 256 + m0b) ^ ((l15 & 7) << 4)));
#pragma unroll
    for (int dt = 0; dt < 4; ++dt) {
      int d = dt * 16 + l15;
      f16x8 vb = *(const f16x8*)(Vl + ((d * 256 + m0b) ^ ((d & 7) << 4)));
      o[dt] = MFMA16(pa, vb, o[dt]);
    }
  }
  _Float16* op = Out + (size_t)(b * 4096 + blockIdx.x * 256 + wid * 16) * 1024 + h * 64;
#pragma unroll
  for (int dt = 0; dt < 4; ++dt)
#pragma unroll
    for (int j = 0; j < 4; ++j) {
      int r = lhi * 4 + j;
      op[(size_t)r * 1024 + dt * 16 + l15] = (_Float16)o[dt][j];
    }
}

// ====== 256x256 GEMM (R9, 907 TF, 0 conflicts): 16x16 frags, cluster-pipelined ======
// reads + true double-buffer. R11 lesson: 32x32-fragment reads measure 4 bank-
// conflicts per ds_read_b128 regardless of swizzle (R4/R11); 16x16 + 3-bit swizzle
// + INT-offset addressing measures 0 (R8/R9). Unchanged from R9/R12.
template <int FINAL>
__global__ __launch_bounds__(512, 2) void k_gemm7(const _Float16* __restrict__ A,
                                                  const _Float16* __restrict__ Bt,
                                                  void* __restrict__ Cout,
                                                  const float* __restrict__ bias,
                                                  int M, int N, int K) {
  __shared__ __align__(16) char lds[131072];
  const int t = threadIdx.x, wid = t >> 6, lane = t & 63;
  const int wr = wid >> 2, wc = wid & 3;  // 2M x 4N wave grid
  const int l15 = lane & 15, lhi = lane >> 4;

  // T1: bijective XCD swizzle (nwg % 8 == 0)
  int nwg = gridDim.x, bid = blockIdx.x;
  int wg = ((nwg & 7) == 0) ? ((bid & 7) * (nwg >> 3) + (bid >> 3)) : bid;
  const int nTN = N >> 8;
  const int tm = wg / nTN, tn = wg % nTN;

  const _Float16* Ag = A + (size_t)tm * 256 * K;
  const _Float16* Bg = Bt + (size_t)tn * 256 * K;
  const size_t stg = (size_t)(wid * 8 + (lane >> 3)) * K +
                     (size_t)(((lane & 7) ^ ((lane >> 3) & 7)) * 8);
  const int dstg = wid * 1024;  // linear wave dest (HW adds lane*16)

  // read swizzle as int offsets: chunk(kk) = (kk*4 + lhi) ^ (l15&7)
  const int x7 = l15 & 7;
  const int cs0 = (lhi ^ x7) << 4;
  const int cs1 = ((4 + lhi) ^ x7) << 4;
  const int aoff = wr * 16384 + l15 * 128;
  const int boff = 32768 + wc * 8192 + l15 * 128;

  f32x4 acc[8][4];
#pragma unroll
  for (int i = 0; i < 8; ++i)
#pragma unroll
    for (int j = 0; j < 4; ++j) acc[i][j] = f32x4{0.f, 0.f, 0.f, 0.f};
  f16x8 a0k0[4], a0k1[4], a1k0[4], a1k1[4];
  f16x8 b00[2], b01[2], b10[2], b11[2];

#define STG_A(T, RB) load_lds16(Ag + stg + (size_t)(RB) * K + (T) * 64, \
                                lds + ((T) & 1) * 65536 + (RB) * 128 + dstg)
#define STG_B(T, RB) load_lds16(Bg + stg + (size_t)(RB) * K + (T) * 64, \
                                lds + ((T) & 1) * 65536 + 32768 + (RB) * 128 + dstg)
#define STG_TILE(T) { STG_A(T, 0); STG_A(T, 64); STG_A(T, 128); STG_A(T, 192);  \
                      STG_B(T, 0); STG_B(T, 64); STG_B(T, 128); STG_B(T, 192); }
#define RDA(DST, BUF, MH, CS) { const int p_ = (BUF) * 65536 + aoff + (MH) * 8192; \
    _Pragma("unroll") for (int mf = 0; mf < 4; ++mf)                               \
      DST[mf] = *(const f16x8*)&lds[p_ + mf * 2048 + (CS)]; }
#define RDB(DST, BUF, NH, CS) { const int q_ = (BUF) * 65536 + boff + (NH) * 4096; \
    _Pragma("unroll") for (int nf = 0; nf < 2; ++nf)                               \
      DST[nf] = *(const f16x8*)&lds[q_ + nf * 2048 + (CS)]; }
#define MMC(MH, NH, AR, BR) { __builtin_amdgcn_s_setprio(1);                       \
    _Pragma("unroll") for (int mf = 0; mf < 4; ++mf)                               \
      _Pragma("unroll") for (int nf = 0; nf < 2; ++nf)                             \
        acc[(MH)*4+mf][(NH)*2+nf] = MFMA16(AR[mf], BR[nf],                         \
                                           acc[(MH)*4+mf][(NH)*2+nf]);             \
    __builtin_amdgcn_s_setprio(0); }
#define VM0 asm volatile("s_waitcnt vmcnt(0)" ::: "memory")
#define BAR __builtin_amdgcn_s_barrier()

#define TILE(BUF, T, STG_ON)                                                       \
  {                                                                                \
    VM0; BAR;                                                                      \
    RDA(a0k0, BUF, 0, cs0); RDB(b00, BUF, 0, cs0);                                 \
    RDB(b10, BUF, 1, cs0);                                                         \
    if (STG_ON) STG_TILE((T) + 1);                                                 \
    MMC(0, 0, a0k0, b00);                                                          \
    RDA(a1k0, BUF, 1, cs0); MMC(0, 1, a0k0, b10);                                  \
    RDA(a1k1, BUF, 1, cs1); MMC(1, 1, a1k0, b10);                                  \
    RDB(b01, BUF, 0, cs1);  MMC(1, 0, a1k0, b00);                                  \
    RDB(b11, BUF, 1, cs1);  MMC(1, 0, a1k1, b01);                                  \
    RDA(a0k1, BUF, 0, cs1); MMC(1, 1, a1k1, b11);                                  \
    MMC(0, 1, a0k1, b11);                                                          \
    MMC(0, 0, a0k1, b01);                                                          \
  }

  const int nT = K >> 6;  // 16 for K=1024 (even, >= 4)

  STG_TILE(0);  // prologue: tile 0 -> buf0

  for (int i = 0; i < (nT >> 1) - 1; ++i) {
    TILE(0, 2 * i, true);
    TILE(1, 2 * i + 1, true);
  }
  TILE(0, nT - 2, true);   // stages tile nT-1 -> buf1
  TILE(1, nT - 1, false);  // last tile: nothing to stage

  // ---- C write: 16x16 C-layout col = l15, row = lhi*4 + reg (verified m89)
  const long rbase = (long)tm * 256 + wr * 128;
  const int cbase = tn * 256 + wc * 64;
#pragma unroll
  for (int mf = 0; mf < 8; ++mf)
#pragma unroll
    for (int nf = 0; nf < 4; ++nf) {
      int c = cbase + nf * 16 + l15;
      float bv = FINAL ? bias[c] : 0.f;
#pragma unroll
      for (int j = 0; j < 4; ++j) {
        long r = rbase + mf * 16 + lhi * 4 + j;
        float v = acc[mf][nf][j];
        if (FINAL) ((float*)Cout)[r * N + c] = v + bv;
        else ((_Float16*)Cout)[r * N + c] = (_Float16)v;
      }
    }
#undef STG_A
#undef STG_B
#undef STG_TILE
#undef RDA
#undef RDB
#undef MMC
#undef TILE
#undef VM0
#undef BAR
}

extern "C" void kernel_launch(void* const* d_in, const int* in_sizes, int n_in,
                              void* d_out, int out_size, void* d_ws, size_t ws_size,
                              hipStream_t stream) {
  const float* x   = (const float*)d_in[0];
  const float* ctx = (const float*)d_in[1];
  const float* Wq  = (const float*)d_in[2];
  const float* Wk  = (const float*)d_in[3];
  const float* Wv  = (const float*)d_in[4];
  const float* Wo  = (const float*)d_in[5];
  const float* bo  = (const float*)d_in[6];

  char* ws = (char*)d_ws;
  _Float16* xh   = (_Float16*)(ws + 0);           // [32768][1024] x-f16; later attnOut
  _Float16* Wqt  = (_Float16*)(ws + 67108864);    // [1024][1024]
  _Float16* Wkt  = (_Float16*)(ws + 69206016);    // [1024][768]
  _Float16* Wvt  = (_Float16*)(ws + 70778880);    // [1024][768]
  _Float16* Wot  = (_Float16*)(ws + 72351744);    // [1024][1024]
  _Float16* ctxh = (_Float16*)(ws + 74448896);    // [616][768]
  _Float16* Kg   = (_Float16*)(ws + 75395072);    // [128][77][64]
  _Float16* Vtg  = (_Float16*)(ws + 76656640);    // [128][64][128]
  _Float16* Qh   = (_Float16*)d_out;              // [32768][1024] f16 scratch in d_out

  // prep: cvt x [0,4096) | cvt ctx [4096,4327) | T(Wq) [4327,4583) | T(Wk)
  // [4583,4775) | T(Wv) [4775,4967) | T(Wo) [4967,5223) | fill Vtg [5223,5735)
  k_prep<<<5735, 256, 0, stream>>>(x, ctx, Wq, Wk, Wv, Wo,
                                   xh, ctxh, Wqt, Wkt, Wvt, Wot, Vtg);
  k_kvproj<<<dim3(39, 64), 64, 0, stream>>>(ctxh, Wkt, Wvt, Kg, Vtg);
  // GEMM1: Q projection -> d_out (f16 scratch); grid 512 (%8==0 for T1)
  k_gemm7<0><<<dim3(512), dim3(512), 0, stream>>>(xh, Wqt, (void*)Qh, nullptr, 32768, 1024, 1024);
  // attention: reads Qh (d_out), writes attnOut -> xh; 256 q-rows/block
  k_attn<<<dim3(16, 128), 1024, 0, stream>>>(Qh, Kg, Vtg, xh);
  // GEMM2: O projection + bias -> d_out (f32)
  k_gemm7<1><<<dim3(512), dim3(512), 0, stream>>>(xh, Wot, d_out, bo, 32768, 1024, 1024);
}

// Round 14
// 245.020 us; speedup vs baseline: 1.0632x; 1.0632x over previous
//
#include <hip/hip_runtime.h>
#include <hip/hip_bf16.h>

typedef _Float16 f16x8 __attribute__((ext_vector_type(8)));
typedef float f32x4 __attribute__((ext_vector_type(4)));

#define MFMA16(a, b, c) __builtin_amdgcn_mfma_f32_16x16x32_f16(a, b, c, 0, 0, 0)

__device__ __forceinline__ void load_lds16(const void* g, void* l) {
  __builtin_amdgcn_global_load_lds(
      (__attribute__((address_space(1))) void*)g,
      (__attribute__((address_space(3))) void*)l, 16, 0, 0);
}

// ============ prep kernel: cvt x, cvt ctx, 4 weight transposes, Vtg pad fill ============
__global__ __launch_bounds__(256) void k_prep(const float* __restrict__ x,
                                              const float* __restrict__ ctx,
                                              const float* __restrict__ Wq,
                                              const float* __restrict__ Wk,
                                              const float* __restrict__ Wv,
                                              const float* __restrict__ Wo,
                                              _Float16* __restrict__ xh,
                                              _Float16* __restrict__ ctxh,
                                              _Float16* __restrict__ Wqt,
                                              _Float16* __restrict__ Wkt,
                                              _Float16* __restrict__ Wvt,
                                              _Float16* __restrict__ Wot,
                                              _Float16* __restrict__ Vtg) {
  __shared__ float tile[64][65];
  const int b = blockIdx.x, t = threadIdx.x;

  if (b < 4096) {  // cvt x
    for (int i = b * 256 + t; i < 4194304; i += 4096 * 256) {
      const float4* p = (const float4*)(x + (size_t)i * 8);
      float4 a = p[0], c = p[1];
      f16x8 v = {(_Float16)a.x, (_Float16)a.y, (_Float16)a.z, (_Float16)a.w,
                 (_Float16)c.x, (_Float16)c.y, (_Float16)c.z, (_Float16)c.w};
      *(f16x8*)(xh + (size_t)i * 8) = v;
    }
    return;
  }
  if (b < 4327) {  // cvt ctx
    int i = (b - 4096) * 256 + t;
    const float4* p = (const float4*)(ctx + (size_t)i * 8);
    float4 a = p[0], c = p[1];
    f16x8 v = {(_Float16)a.x, (_Float16)a.y, (_Float16)a.z, (_Float16)a.w,
               (_Float16)c.x, (_Float16)c.y, (_Float16)c.z, (_Float16)c.w};
    *(f16x8*)(ctxh + (size_t)i * 8) = v;
    return;
  }
  if (b >= 5223) {  // zero Vtg
    int i = (b - 5223) * 256 + t;
    ((f16x8*)Vtg)[i] = f16x8{};
    return;
  }
  const float* tin;
  _Float16* tout;
  int TK, TN, i;
  if (b < 4583)      { tin = Wq; tout = Wqt; TK = 1024; TN = 1024; i = b - 4327; }
  else if (b < 4775) { tin = Wk; tout = Wkt; TK = 768;  TN = 1024; i = b - 4583; }
  else if (b < 4967) { tin = Wv; tout = Wvt; TK = 768;  TN = 1024; i = b - 4775; }
  else               { tin = Wo; tout = Wot; TK = 1024; TN = 1024; i = b - 4967; }
  int n0 = (i & 15) * 64, k0 = (i >> 4) * 64;
  {
    int nn = t & 63, kb = t >> 6;
#pragma unroll
    for (int s = 0; s < 16; ++s) {
      int kk = kb + s * 4;
      tile[kk][nn] = tin[(size_t)(k0 + kk) * TN + n0 + nn];
    }
  }
  __syncthreads();
  {
    int kk = t & 63, nb = t >> 6;
#pragma unroll
    for (int s = 0; s < 16; ++s) {
      int nn = nb + s * 4;
      tout[(size_t)(n0 + nn) * TK + k0 + kk] = (_Float16)tile[kk][nn];
    }
  }
}

// ---------------- K/V projection: ctxh[616][768] @ W^T -> heads ----------------
__global__ __launch_bounds__(64) void k_kvproj(const _Float16* __restrict__ ctxh,
                                               const _Float16* __restrict__ Wkt,
                                               const _Float16* __restrict__ Wvt,
                                               _Float16* __restrict__ Kg,
                                               _Float16* __restrict__ Vtg) {
  int mt = blockIdx.x, nt = blockIdx.y;
  int lane = threadIdx.x;
  int l15 = lane & 15, lhi = lane >> 4;
  int arow = mt * 16 + l15;
  if (arow > 615) arow = 615;  // clamp; masked at write
  const _Float16* ap = ctxh + (size_t)arow * 768 + lhi * 8;
  const _Float16* kp = Wkt + (size_t)(nt * 16 + l15) * 768 + lhi * 8;
  const _Float16* vp = Wvt + (size_t)(nt * 16 + l15) * 768 + lhi * 8;
  f32x4 ak = {0.f, 0.f, 0.f, 0.f}, av = {0.f, 0.f, 0.f, 0.f};
#pragma unroll 4
  for (int ks = 0; ks < 24; ++ks) {
    f16x8 a = *(const f16x8*)(ap + ks * 32);
    f16x8 bk = *(const f16x8*)(kp + ks * 32);
    f16x8 bv = *(const f16x8*)(vp + ks * 32);
    ak = MFMA16(a, bk, ak);
    av = MFMA16(a, bv, av);
  }
  int n = nt * 16 + l15, h = n >> 6, d = n & 63;
#pragma unroll
  for (int j = 0; j < 4; ++j) {
    int gm = mt * 16 + lhi * 4 + j;
    if (gm < 616) {
      int b = gm / 77, m = gm - b * 77;
      Kg[((size_t)(b * 16 + h) * 77 + m) * 64 + d] = (_Float16)ak[j];
      Vtg[((size_t)(b * 16 + h) * 64 + d) * 128 + m] = (_Float16)av[j];
    }
  }
}

// ====== 256x256 GEMM (R9 schedule) + fused attention epilogue (MODE 0) ======
// MODE 0 (Q-proj): after the K-loop each wave holds Q for 128 rows x ONE head
// (head = tn*4+wc) in acc. Epilogue: barrier; dump Q->LDS (16KB/wave, XOR swizzle);
// per 16-row group run the verified k_attn wave body with K/V fragments loaded
// DIRECTLY FROM GLOBAL (K/V = 3.3MB total, L2-resident); write attnOut. This
// removes the attn kernel + Q's 67MB write + 67MB read.
// MODE 1 (O-proj): f32 out + bias (unchanged R9 epilogue).
// GEMM core: 907 TF, 0 bank conflicts (16x16 frags, 3-bit swizzle, INT offsets,
// true double-buffer, one vmcnt(0)+barrier per K-tile, cluster-ahead reads).
template <int MODE>
__global__ __launch_bounds__(512, 2) void k_gemm9(const _Float16* __restrict__ A,
                                                  const _Float16* __restrict__ Bt,
                                                  void* __restrict__ Cout,
                                                  const float* __restrict__ bias,
                                                  const _Float16* __restrict__ Kg,
                                                  const _Float16* __restrict__ Vtg,
                                                  int M, int N, int K) {
  __shared__ __align__(16) char lds[MODE == 0 ? 163840 : 131072];
  const int t = threadIdx.x, wid = t >> 6, lane = t & 63;
  const int wr = wid >> 2, wc = wid & 3;  // 2M x 4N wave grid
  const int l15 = lane & 15, lhi = lane >> 4;

  // T1: bijective XCD swizzle (nwg % 8 == 0)
  int nwg = gridDim.x, bid = blockIdx.x;
  int wg = ((nwg & 7) == 0) ? ((bid & 7) * (nwg >> 3) + (bid >> 3)) : bid;
  const int nTN = N >> 8;
  const int tm = wg / nTN, tn = wg % nTN;

  const _Float16* Ag = A + (size_t)tm * 256 * K;
  const _Float16* Bg = Bt + (size_t)tn * 256 * K;
  const size_t stg = (size_t)(wid * 8 + (lane >> 3)) * K +
                     (size_t)(((lane & 7) ^ ((lane >> 3) & 7)) * 8);
  const int dstg = wid * 1024;

  const int x7 = l15 & 7;
  const int cs0 = (lhi ^ x7) << 4;
  const int cs1 = ((4 + lhi) ^ x7) << 4;
  const int aoff = wr * 16384 + l15 * 128;
  const int boff = 32768 + wc * 8192 + l15 * 128;

  f32x4 acc[8][4];
#pragma unroll
  for (int i = 0; i < 8; ++i)
#pragma unroll
    for (int j = 0; j < 4; ++j) acc[i][j] = f32x4{0.f, 0.f, 0.f, 0.f};
  f16x8 a0k0[4], a0k1[4], a1k0[4], a1k1[4];
  f16x8 b00[2], b01[2], b10[2], b11[2];

#define STG_A(T, RB) load_lds16(Ag + stg + (size_t)(RB) * K + (T) * 64, \
                                lds + ((T) & 1) * 65536 + (RB) * 128 + dstg)
#define STG_B(T, RB) load_lds16(Bg + stg + (size_t)(RB) * K + (T) * 64, \
                                lds + ((T) & 1) * 65536 + 32768 + (RB) * 128 + dstg)
#define STG_TILE(T) { STG_A(T, 0); STG_A(T, 64); STG_A(T, 128); STG_A(T, 192);  \
                      STG_B(T, 0); STG_B(T, 64); STG_B(T, 128); STG_B(T, 192); }
#define RDA(DST, BUF, MH, CS) { const int p_ = (BUF) * 65536 + aoff + (MH) * 8192; \
    _Pragma("unroll") for (int mf = 0; mf < 4; ++mf)                               \
      DST[mf] = *(const f16x8*)&lds[p_ + mf * 2048 + (CS)]; }
#define RDB(DST, BUF, NH, CS) { const int q_ = (BUF) * 65536 + boff + (NH) * 4096; \
    _Pragma("unroll") for (int nf = 0; nf < 2; ++nf)                               \
      DST[nf] = *(const f16x8*)&lds[q_ + nf * 2048 + (CS)]; }
#define MMC(MH, NH, AR, BR) { __builtin_amdgcn_s_setprio(1);                       \
    _Pragma("unroll") for (int mf = 0; mf < 4; ++mf)                               \
      _Pragma("unroll") for (int nf = 0; nf < 2; ++nf)                             \
        acc[(MH)*4+mf][(NH)*2+nf] = MFMA16(AR[mf], BR[nf],                         \
                                           acc[(MH)*4+mf][(NH)*2+nf]);             \
    __builtin_amdgcn_s_setprio(0); }
#define VM0 asm volatile("s_waitcnt vmcnt(0)" ::: "memory")
#define BAR __builtin_amdgcn_s_barrier()

#define TILE(BUF, T, STG_ON)                                                       \
  {                                                                                \
    VM0; BAR;                                                                      \
    RDA(a0k0, BUF, 0, cs0); RDB(b00, BUF, 0, cs0);                                 \
    RDB(b10, BUF, 1, cs0);                                                         \
    if (STG_ON) STG_TILE((T) + 1);                                                 \
    MMC(0, 0, a0k0, b00);                                                          \
    RDA(a1k0, BUF, 1, cs0); MMC(0, 1, a0k0, b10);                                  \
    RDA(a1k1, BUF, 1, cs1); MMC(1, 1, a1k0, b10);                                  \
    RDB(b01, BUF, 0, cs1);  MMC(1, 0, a1k0, b00);                                  \
    RDB(b11, BUF, 1, cs1);  MMC(1, 0, a1k1, b01);                                  \
    RDA(a0k1, BUF, 0, cs1); MMC(1, 1, a1k1, b11);                                  \
    MMC(0, 1, a0k1, b11);                                                          \
    MMC(0, 0, a0k1, b01);                                                          \
  }

  const int nT = K >> 6;

  STG_TILE(0);

  for (int i = 0; i < (nT >> 1) - 1; ++i) {
    TILE(0, 2 * i, true);
    TILE(1, 2 * i + 1, true);
  }
  TILE(0, nT - 2, true);
  TILE(1, nT - 1, false);

  if (MODE == 1) {
    // ---- plain epilogue: f32 + bias
    const long rbase = (long)tm * 256 + wr * 128;
    const int cbase = tn * 256 + wc * 64;
#pragma unroll
    for (int mf = 0; mf < 8; ++mf)
#pragma unroll
      for (int nf = 0; nf < 4; ++nf) {
        int c = cbase + nf * 16 + l15;
        float bv = bias[c];
#pragma unroll
        for (int j = 0; j < 4; ++j) {
          long r = rbase + mf * 16 + lhi * 4 + j;
          ((float*)Cout)[r * N + c] = acc[mf][nf][j] + bv;
        }
      }
    return;
  }

  // =================== MODE 0: fused attention epilogue ===================
  // wave owns q-rows [tm*256 + wr*128, +128) x head h = tn*4 + wc.
  BAR;  // all waves done with K-loop LDS before repurposing

  const int h = tn * 4 + wc;
  const int bh = (tm >> 4) * 16 + h;  // batch = tm/16 (4096 rows per batch)
  const _Float16* Kgp = Kg + (size_t)bh * (77 * 64);
  const _Float16* Vgp = Vtg + (size_t)bh * (64 * 128);

  // dump Q (f32 acc -> f16) into per-wave 16KB LDS: [128 rows][64 d],
  // byte = row*128 + d*2, chunk XOR'd by row&7 (same swizzle family as reads)
  const int qbase = wid * 16384;
#pragma unroll
  for (int mf = 0; mf < 8; ++mf)
#pragma unroll
    for (int nf = 0; nf < 4; ++nf)
#pragma unroll
      for (int j = 0; j < 4; ++j) {
        int row = mf * 16 + lhi * 4 + j;
        int d = nf * 16 + l15;
        int by = (row * 128 + d * 2) ^ ((row & 7) << 4);
        *(_Float16*)&lds[qbase + by] = (_Float16)acc[mf][nf][j];
      }

  // per-wave P region (4KB) at 128KB + wid*4KB; zero once (covers m 80..95 pad)
  const int pbase = 131072 + wid * 4096;
#pragma unroll
  for (int i = 0; i < 4; ++i)
    *(f16x8*)&lds[pbase + lane * 64 + i * 16] = f16x8{};
  // no barrier needed: everything below is wave-private (lgkm ordering per wave)

  const long orow0 = (long)tm * 256 + wr * 128;
  _Float16* aOut = (_Float16*)Cout;

  for (int mf = 0; mf < 8; ++mf) {
    // Q A-frags from LDS: rows mf*16 + l15, k = lhi*8 (+32)
    const int qm = qbase + mf * 2048 + l15 * 128;
    f16x8 q0 = *(const f16x8*)&lds[qm + cs0];
    f16x8 q1 = *(const f16x8*)&lds[qm + cs1];

    float e[5][4];
    float mx[4] = {-1e30f, -1e30f, -1e30f, -1e30f};
#pragma unroll
    for (int ct = 0; ct < 5; ++ct) {
      int m = ct * 16 + l15;
      // K B-frags straight from global (L2-hot); m>=77 lands in adjacent
      // KV data (finite) and is masked below (contaminates only col m).
      f16x8 k0 = *(const f16x8*)(Kgp + m * 64 + lhi * 8);
      f16x8 k1 = *(const f16x8*)(Kgp + m * 64 + 32 + lhi * 8);
      f32x4 s = {0.f, 0.f, 0.f, 0.f};
      s = MFMA16(q0, k0, s);
      s = MFMA16(q1, k1, s);
      bool valid = m < 77;
#pragma unroll
      for (int j = 0; j < 4; ++j) {
        float v = valid ? s[j] * 0.125f : -1e30f;
        e[ct][j] = v;
        mx[j] = fmaxf(mx[j], v);
      }
    }
#pragma unroll
    for (int off = 1; off < 16; off <<= 1)
#pragma unroll
      for (int j = 0; j < 4; ++j) mx[j] = fmaxf(mx[j], __shfl_xor(mx[j], off, 64));
    float sm[4] = {0.f, 0.f, 0.f, 0.f};
#pragma unroll
    for (int ct = 0; ct < 5; ++ct)
#pragma unroll
      for (int j = 0; j < 4; ++j) {
        float ev = __expf(e[ct][j] - mx[j]);
        e[ct][j] = ev;
        sm[j] += ev;
      }
#pragma unroll
    for (int off = 1; off < 16; off <<= 1)
#pragma unroll
      for (int j = 0; j < 4; ++j) sm[j] += __shfl_xor(sm[j], off, 64);
    float rs[4];
#pragma unroll
    for (int j = 0; j < 4; ++j) rs[j] = 1.0f / sm[j];

    // write P to per-wave LDS in A-frag layout [16 r][128 m] (swizzled)
#pragma unroll
    for (int ct = 0; ct < 5; ++ct) {
      int m = ct * 16 + l15;
#pragma unroll
      for (int j = 0; j < 4; ++j) {
        int r = lhi * 4 + j;
        *(_Float16*)&lds[pbase + ((r * 256 + m * 2) ^ ((r & 7) << 4))] =
            (_Float16)(e[ct][j] * rs[j]);
      }
    }

    // PV: out[r][d] = sum_m P[r][m] * V^T[d][m]; V from global
    f32x4 o[4] = {{0.f,0.f,0.f,0.f},{0.f,0.f,0.f,0.f},{0.f,0.f,0.f,0.f},{0.f,0.f,0.f,0.f}};
#pragma unroll
    for (int ks = 0; ks < 3; ++ks) {
      int m0b = ks * 64 + lhi * 16;  // byte offset within 256B P-row
      f16x8 pa = *(const f16x8*)&lds[pbase + ((l15 * 256 + m0b) ^ ((l15 & 7) << 4))];
#pragma unroll
      for (int dt = 0; dt < 4; ++dt) {
        int d = dt * 16 + l15;
        f16x8 vb = *(const f16x8*)(Vgp + d * 128 + ks * 32 + lhi * 8);
        o[dt] = MFMA16(pa, vb, o[dt]);
      }
    }
    _Float16* op = aOut + (size_t)(orow0 + mf * 16 + lhi * 4) * 1024 + h * 64;
#pragma unroll
    for (int dt = 0; dt < 4; ++dt)
#pragma unroll
      for (int j = 0; j < 4; ++j)
        op[(size_t)j * 1024 + dt * 16 + l15] = (_Float16)o[dt][j];
  }
#undef STG_A
#undef STG_B
#undef STG_TILE
#undef RDA
#undef RDB
#undef MMC
#undef TILE
#undef VM0
#undef BAR
}

extern "C" void kernel_launch(void* const* d_in, const int* in_sizes, int n_in,
                              void* d_out, int out_size, void* d_ws, size_t ws_size,
                              hipStream_t stream) {
  const float* x   = (const float*)d_in[0];
  const float* ctx = (const float*)d_in[1];
  const float* Wq  = (const float*)d_in[2];
  const float* Wk  = (const float*)d_in[3];
  const float* Wv  = (const float*)d_in[4];
  const float* Wo  = (const float*)d_in[5];
  const float* bo  = (const float*)d_in[6];

  // ws layout (145.9 MB total; ws>=146MB verified by R1/R2 bit-identical absmax)
  char* ws = (char*)d_ws;
  _Float16* xh   = (_Float16*)(ws + 0);           // [32768][1024] x-f16
  _Float16* Wqt  = (_Float16*)(ws + 67108864);    // [1024][1024]
  _Float16* Wkt  = (_Float16*)(ws + 69206016);    // [1024][768]
  _Float16* Wvt  = (_Float16*)(ws + 70778880);    // [1024][768]
  _Float16* Wot  = (_Float16*)(ws + 72351744);    // [1024][1024]
  _Float16* ctxh = (_Float16*)(ws + 74448896);    // [616][768]
  _Float16* Kg   = (_Float16*)(ws + 75395072);    // [128][77][64]
  _Float16* Vtg  = (_Float16*)(ws + 76656640);    // [128][64][128]
  _Float16* aOut = (_Float16*)(ws + 78774272);    // [32768][1024] attnOut (end 145.9MB)

  k_prep<<<5735, 256, 0, stream>>>(x, ctx, Wq, Wk, Wv, Wo,
                                   xh, ctxh, Wqt, Wkt, Wvt, Wot, Vtg);
  k_kvproj<<<dim3(39, 64), 64, 0, stream>>>(ctxh, Wkt, Wvt, Kg, Vtg);
  // GEMM1 + fused attention: writes attnOut directly (no Qh round trip)
  k_gemm9<0><<<dim3(512), dim3(512), 0, stream>>>(xh, Wqt, (void*)aOut, nullptr,
                                                  Kg, Vtg, 32768, 1024, 1024);
  // GEMM2: O projection + bias -> d_out (f32)
  k_gemm9<1><<<dim3(512), dim3(512), 0, stream>>>(aOut, Wot, d_out, bo,
                                                  nullptr, nullptr, 32768, 1024, 1024);
}

// Round 15
// 244.083 us; speedup vs baseline: 1.0672x; 1.0038x over previous
//
#include <hip/hip_runtime.h>
#include <hip/hip_bf16.h>

typedef _Float16 f16x8 __attribute__((ext_vector_type(8)));
typedef float f32x4 __attribute__((ext_vector_type(4)));

#define MFMA16(a, b, c) __builtin_amdgcn_mfma_f32_16x16x32_f16(a, b, c, 0, 0, 0)

__device__ __forceinline__ void load_lds16(const void* g, void* l) {
  __builtin_amdgcn_global_load_lds(
      (__attribute__((address_space(1))) void*)g,
      (__attribute__((address_space(3))) void*)l, 16, 0, 0);
}

// ============ prep kernel: cvt x, cvt ctx, 4 weight transposes, Vtg pad fill ============
__global__ __launch_bounds__(256) void k_prep(const float* __restrict__ x,
                                              const float* __restrict__ ctx,
                                              const float* __restrict__ Wq,
                                              const float* __restrict__ Wk,
                                              const float* __restrict__ Wv,
                                              const float* __restrict__ Wo,
                                              _Float16* __restrict__ xh,
                                              _Float16* __restrict__ ctxh,
                                              _Float16* __restrict__ Wqt,
                                              _Float16* __restrict__ Wkt,
                                              _Float16* __restrict__ Wvt,
                                              _Float16* __restrict__ Wot,
                                              _Float16* __restrict__ Vtg) {
  __shared__ float tile[64][65];
  const int b = blockIdx.x, t = threadIdx.x;

  if (b < 4096) {  // cvt x
    for (int i = b * 256 + t; i < 4194304; i += 4096 * 256) {
      const float4* p = (const float4*)(x + (size_t)i * 8);
      float4 a = p[0], c = p[1];
      f16x8 v = {(_Float16)a.x, (_Float16)a.y, (_Float16)a.z, (_Float16)a.w,
                 (_Float16)c.x, (_Float16)c.y, (_Float16)c.z, (_Float16)c.w};
      *(f16x8*)(xh + (size_t)i * 8) = v;
    }
    return;
  }
  if (b < 4327) {  // cvt ctx
    int i = (b - 4096) * 256 + t;
    const float4* p = (const float4*)(ctx + (size_t)i * 8);
    float4 a = p[0], c = p[1];
    f16x8 v = {(_Float16)a.x, (_Float16)a.y, (_Float16)a.z, (_Float16)a.w,
               (_Float16)c.x, (_Float16)c.y, (_Float16)c.z, (_Float16)c.w};
    *(f16x8*)(ctxh + (size_t)i * 8) = v;
    return;
  }
  if (b >= 5223) {  // zero Vtg
    int i = (b - 5223) * 256 + t;
    ((f16x8*)Vtg)[i] = f16x8{};
    return;
  }
  const float* tin;
  _Float16* tout;
  int TK, TN, i;
  if (b < 4583)      { tin = Wq; tout = Wqt; TK = 1024; TN = 1024; i = b - 4327; }
  else if (b < 4775) { tin = Wk; tout = Wkt; TK = 768;  TN = 1024; i = b - 4583; }
  else if (b < 4967) { tin = Wv; tout = Wvt; TK = 768;  TN = 1024; i = b - 4775; }
  else               { tin = Wo; tout = Wot; TK = 1024; TN = 1024; i = b - 4967; }
  int n0 = (i & 15) * 64, k0 = (i >> 4) * 64;
  {
    int nn = t & 63, kb = t >> 6;
#pragma unroll
    for (int s = 0; s < 16; ++s) {
      int kk = kb + s * 4;
      tile[kk][nn] = tin[(size_t)(k0 + kk) * TN + n0 + nn];
    }
  }
  __syncthreads();
  {
    int kk = t & 63, nb = t >> 6;
#pragma unroll
    for (int s = 0; s < 16; ++s) {
      int nn = nb + s * 4;
      tout[(size_t)(n0 + nn) * TK + k0 + kk] = (_Float16)tile[kk][nn];
    }
  }
}

// ---------------- K/V projection: ctxh[616][768] @ W^T -> heads ----------------
__global__ __launch_bounds__(64) void k_kvproj(const _Float16* __restrict__ ctxh,
                                               const _Float16* __restrict__ Wkt,
                                               const _Float16* __restrict__ Wvt,
                                               _Float16* __restrict__ Kg,
                                               _Float16* __restrict__ Vtg) {
  int mt = blockIdx.x, nt = blockIdx.y;
  int lane = threadIdx.x;
  int l15 = lane & 15, lhi = lane >> 4;
  int arow = mt * 16 + l15;
  if (arow > 615) arow = 615;  // clamp; masked at write
  const _Float16* ap = ctxh + (size_t)arow * 768 + lhi * 8;
  const _Float16* kp = Wkt + (size_t)(nt * 16 + l15) * 768 + lhi * 8;
  const _Float16* vp = Wvt + (size_t)(nt * 16 + l15) * 768 + lhi * 8;
  f32x4 ak = {0.f, 0.f, 0.f, 0.f}, av = {0.f, 0.f, 0.f, 0.f};
#pragma unroll 4
  for (int ks = 0; ks < 24; ++ks) {
    f16x8 a = *(const f16x8*)(ap + ks * 32);
    f16x8 bk = *(const f16x8*)(kp + ks * 32);
    f16x8 bv = *(const f16x8*)(vp + ks * 32);
    ak = MFMA16(a, bk, ak);
    av = MFMA16(a, bv, av);
  }
  int n = nt * 16 + l15, h = n >> 6, d = n & 63;
#pragma unroll
  for (int j = 0; j < 4; ++j) {
    int gm = mt * 16 + lhi * 4 + j;
    if (gm < 616) {
      int b = gm / 77, m = gm - b * 77;
      Kg[((size_t)(b * 16 + h) * 77 + m) * 64 + d] = (_Float16)ak[j];
      Vtg[((size_t)(b * 16 + h) * 64 + d) * 128 + m] = (_Float16)av[j];
    }
  }
}

// ====== 256x256 GEMM (R9 schedule) + fused attention epilogue (MODE 0) ======
// MODE 0 (Q-proj): after the K-loop each wave holds Q for 128 rows x ONE head
// (head = tn*4+wc). Epilogue: barrier; dump Q->LDS (acc dead after); hoist ALL
// K/V fragments into registers ONCE (R15: they are mf-invariant; R14 re-loaded
// them from global 8x = 154 redundant loads/thread); then per 16-row group:
// QK^T -> wave softmax -> P via per-wave LDS -> PV -> write attnOut.
// Occupancy is LDS-bound (160KB -> 1 block/CU = 2 waves/SIMD), so the ~90 extra
// epilogue VGPRs are free (2 waves needs <=256 VGPR).
// MODE 1 (O-proj): f32 out + bias.
template <int MODE>
__global__ __launch_bounds__(512, 2) void k_gemm9(const _Float16* __restrict__ A,
                                                  const _Float16* __restrict__ Bt,
                                                  void* __restrict__ Cout,
                                                  const float* __restrict__ bias,
                                                  const _Float16* __restrict__ Kg,
                                                  const _Float16* __restrict__ Vtg,
                                                  int M, int N, int K) {
  __shared__ __align__(16) char lds[MODE == 0 ? 163840 : 131072];
  const int t = threadIdx.x, wid = t >> 6, lane = t & 63;
  const int wr = wid >> 2, wc = wid & 3;  // 2M x 4N wave grid
  const int l15 = lane & 15, lhi = lane >> 4;

  // T1: bijective XCD swizzle (nwg % 8 == 0)
  int nwg = gridDim.x, bid = blockIdx.x;
  int wg = ((nwg & 7) == 0) ? ((bid & 7) * (nwg >> 3) + (bid >> 3)) : bid;
  const int nTN = N >> 8;
  const int tm = wg / nTN, tn = wg % nTN;

  const _Float16* Ag = A + (size_t)tm * 256 * K;
  const _Float16* Bg = Bt + (size_t)tn * 256 * K;
  const size_t stg = (size_t)(wid * 8 + (lane >> 3)) * K +
                     (size_t)(((lane & 7) ^ ((lane >> 3) & 7)) * 8);
  const int dstg = wid * 1024;

  const int x7 = l15 & 7;
  const int cs0 = (lhi ^ x7) << 4;
  const int cs1 = ((4 + lhi) ^ x7) << 4;
  const int aoff = wr * 16384 + l15 * 128;
  const int boff = 32768 + wc * 8192 + l15 * 128;

  f32x4 acc[8][4];
#pragma unroll
  for (int i = 0; i < 8; ++i)
#pragma unroll
    for (int j = 0; j < 4; ++j) acc[i][j] = f32x4{0.f, 0.f, 0.f, 0.f};
  f16x8 a0k0[4], a0k1[4], a1k0[4], a1k1[4];
  f16x8 b00[2], b01[2], b10[2], b11[2];

#define STG_A(T, RB) load_lds16(Ag + stg + (size_t)(RB) * K + (T) * 64, \
                                lds + ((T) & 1) * 65536 + (RB) * 128 + dstg)
#define STG_B(T, RB) load_lds16(Bg + stg + (size_t)(RB) * K + (T) * 64, \
                                lds + ((T) & 1) * 65536 + 32768 + (RB) * 128 + dstg)
#define STG_TILE(T) { STG_A(T, 0); STG_A(T, 64); STG_A(T, 128); STG_A(T, 192);  \
                      STG_B(T, 0); STG_B(T, 64); STG_B(T, 128); STG_B(T, 192); }
#define RDA(DST, BUF, MH, CS) { const int p_ = (BUF) * 65536 + aoff + (MH) * 8192; \
    _Pragma("unroll") for (int mf = 0; mf < 4; ++mf)                               \
      DST[mf] = *(const f16x8*)&lds[p_ + mf * 2048 + (CS)]; }
#define RDB(DST, BUF, NH, CS) { const int q_ = (BUF) * 65536 + boff + (NH) * 4096; \
    _Pragma("unroll") for (int nf = 0; nf < 2; ++nf)                               \
      DST[nf] = *(const f16x8*)&lds[q_ + nf * 2048 + (CS)]; }
#define MMC(MH, NH, AR, BR) { __builtin_amdgcn_s_setprio(1);                       \
    _Pragma("unroll") for (int mf = 0; mf < 4; ++mf)                               \
      _Pragma("unroll") for (int nf = 0; nf < 2; ++nf)                             \
        acc[(MH)*4+mf][(NH)*2+nf] = MFMA16(AR[mf], BR[nf],                         \
                                           acc[(MH)*4+mf][(NH)*2+nf]);             \
    __builtin_amdgcn_s_setprio(0); }
#define VM0 asm volatile("s_waitcnt vmcnt(0)" ::: "memory")
#define BAR __builtin_amdgcn_s_barrier()

#define TILE(BUF, T, STG_ON)                                                       \
  {                                                                                \
    VM0; BAR;                                                                      \
    RDA(a0k0, BUF, 0, cs0); RDB(b00, BUF, 0, cs0);                                 \
    RDB(b10, BUF, 1, cs0);                                                         \
    if (STG_ON) STG_TILE((T) + 1);                                                 \
    MMC(0, 0, a0k0, b00);                                                          \
    RDA(a1k0, BUF, 1, cs0); MMC(0, 1, a0k0, b10);                                  \
    RDA(a1k1, BUF, 1, cs1); MMC(1, 1, a1k0, b10);                                  \
    RDB(b01, BUF, 0, cs1);  MMC(1, 0, a1k0, b00);                                  \
    RDB(b11, BUF, 1, cs1);  MMC(1, 0, a1k1, b01);                                  \
    RDA(a0k1, BUF, 0, cs1); MMC(1, 1, a1k1, b11);                                  \
    MMC(0, 1, a0k1, b11);                                                          \
    MMC(0, 0, a0k1, b01);                                                          \
  }

  const int nT = K >> 6;

  STG_TILE(0);

  for (int i = 0; i < (nT >> 1) - 1; ++i) {
    TILE(0, 2 * i, true);
    TILE(1, 2 * i + 1, true);
  }
  TILE(0, nT - 2, true);
  TILE(1, nT - 1, false);

  if (MODE == 1) {
    // ---- plain epilogue: f32 + bias
    const long rbase = (long)tm * 256 + wr * 128;
    const int cbase = tn * 256 + wc * 64;
#pragma unroll
    for (int mf = 0; mf < 8; ++mf)
#pragma unroll
      for (int nf = 0; nf < 4; ++nf) {
        int c = cbase + nf * 16 + l15;
        float bv = bias[c];
#pragma unroll
        for (int j = 0; j < 4; ++j) {
          long r = rbase + mf * 16 + lhi * 4 + j;
          ((float*)Cout)[r * N + c] = acc[mf][nf][j] + bv;
        }
      }
    return;
  }

  // =================== MODE 0: fused attention epilogue ===================
  // wave owns q-rows [tm*256 + wr*128, +128) x head h = tn*4 + wc.
  BAR;  // all waves done with K-loop LDS before repurposing

  const int h = tn * 4 + wc;
  const int bh = (tm >> 4) * 16 + h;  // batch = tm/16 (4096 rows per batch)
  const _Float16* Kgp = Kg + (size_t)bh * (77 * 64);
  const _Float16* Vgp = Vtg + (size_t)bh * (64 * 128);

  // dump Q (f32 acc -> f16) into per-wave 16KB LDS: [128 rows][64 d],
  // byte = row*128 + d*2, chunk XOR'd by row&7. acc is DEAD after this.
  const int qbase = wid * 16384;
#pragma unroll
  for (int mf = 0; mf < 8; ++mf)
#pragma unroll
    for (int nf = 0; nf < 4; ++nf)
#pragma unroll
      for (int j = 0; j < 4; ++j) {
        int row = mf * 16 + lhi * 4 + j;
        int d = nf * 16 + l15;
        int by = (row * 128 + d * 2) ^ ((row & 7) << 4);
        *(_Float16*)&lds[qbase + by] = (_Float16)acc[mf][nf][j];
      }

  // per-wave P region (4KB) at 128KB + wid*4KB; zero once (covers m 80..95 pad)
  const int pbase = 131072 + wid * 4096;
#pragma unroll
  for (int i = 0; i < 4; ++i)
    *(f16x8*)&lds[pbase + lane * 64 + i * 16] = f16x8{};
  // wave-private below (lgkm ordering per wave); no barrier needed.

  // ---- R15: hoist mf-invariant K/V fragments into registers (loaded ONCE).
  // K: m = ct*16 + l15 (m>=77 reads adjacent finite data, masked below).
  // V: V^T[d = dt*16 + l15][m = ks*32 + lhi*8 ..+7].
  f16x8 kf[5][2];
#pragma unroll
  for (int ct = 0; ct < 5; ++ct) {
    int m = ct * 16 + l15;
    kf[ct][0] = *(const f16x8*)(Kgp + m * 64 + lhi * 8);
    kf[ct][1] = *(const f16x8*)(Kgp + m * 64 + 32 + lhi * 8);
  }
  f16x8 vf[3][4];
#pragma unroll
  for (int ks = 0; ks < 3; ++ks)
#pragma unroll
    for (int dt = 0; dt < 4; ++dt) {
      int d = dt * 16 + l15;
      vf[ks][dt] = *(const f16x8*)(Vgp + d * 128 + ks * 32 + lhi * 8);
    }

  const long orow0 = (long)tm * 256 + wr * 128;
  _Float16* aOut = (_Float16*)Cout;

  for (int mf = 0; mf < 8; ++mf) {
    // Q A-frags from LDS: rows mf*16 + l15, k = lhi*8 (+32)
    const int qm = qbase + mf * 2048 + l15 * 128;
    f16x8 q0 = *(const f16x8*)&lds[qm + cs0];
    f16x8 q1 = *(const f16x8*)&lds[qm + cs1];

    float e[5][4];
    float mx[4] = {-1e30f, -1e30f, -1e30f, -1e30f};
#pragma unroll
    for (int ct = 0; ct < 5; ++ct) {
      f32x4 s = {0.f, 0.f, 0.f, 0.f};
      s = MFMA16(q0, kf[ct][0], s);
      s = MFMA16(q1, kf[ct][1], s);
      bool valid = (ct * 16 + l15) < 77;
#pragma unroll
      for (int j = 0; j < 4; ++j) {
        float v = valid ? s[j] * 0.125f : -1e30f;
        e[ct][j] = v;
        mx[j] = fmaxf(mx[j], v);
      }
    }
#pragma unroll
    for (int off = 1; off < 16; off <<= 1)
#pragma unroll
      for (int j = 0; j < 4; ++j) mx[j] = fmaxf(mx[j], __shfl_xor(mx[j], off, 64));
    float sm[4] = {0.f, 0.f, 0.f, 0.f};
#pragma unroll
    for (int ct = 0; ct < 5; ++ct)
#pragma unroll
      for (int j = 0; j < 4; ++j) {
        float ev = __expf(e[ct][j] - mx[j]);
        e[ct][j] = ev;
        sm[j] += ev;
      }
#pragma unroll
    for (int off = 1; off < 16; off <<= 1)
#pragma unroll
      for (int j = 0; j < 4; ++j) sm[j] += __shfl_xor(sm[j], off, 64);
    float rs[4];
#pragma unroll
    for (int j = 0; j < 4; ++j) rs[j] = 1.0f / sm[j];

    // write P to per-wave LDS in A-frag layout [16 r][128 m] (swizzled)
#pragma unroll
    for (int ct = 0; ct < 5; ++ct) {
      int m = ct * 16 + l15;
#pragma unroll
      for (int j = 0; j < 4; ++j) {
        int r = lhi * 4 + j;
        *(_Float16*)&lds[pbase + ((r * 256 + m * 2) ^ ((r & 7) << 4))] =
            (_Float16)(e[ct][j] * rs[j]);
      }
    }

    // PV: out[r][d] = sum_m P[r][m] * V^T[d][m]; V from registers
    f32x4 o[4] = {{0.f,0.f,0.f,0.f},{0.f,0.f,0.f,0.f},{0.f,0.f,0.f,0.f},{0.f,0.f,0.f,0.f}};
#pragma unroll
    for (int ks = 0; ks < 3; ++ks) {
      int m0b = ks * 64 + lhi * 16;  // byte offset within 256B P-row
      f16x8 pa = *(const f16x8*)&lds[pbase + ((l15 * 256 + m0b) ^ ((l15 & 7) << 4))];
#pragma unroll
      for (int dt = 0; dt < 4; ++dt)
        o[dt] = MFMA16(pa, vf[ks][dt], o[dt]);
    }
    _Float16* op = aOut + (size_t)(orow0 + mf * 16 + lhi * 4) * 1024 + h * 64;
#pragma unroll
    for (int dt = 0; dt < 4; ++dt)
#pragma unroll
      for (int j = 0; j < 4; ++j)
        op[(size_t)j * 1024 + dt * 16 + l15] = (_Float16)o[dt][j];
  }
#undef STG_A
#undef STG_B
#undef STG_TILE
#undef RDA
#undef RDB
#undef MMC
#undef TILE
#undef VM0
#undef BAR
}

extern "C" void kernel_launch(void* const* d_in, const int* in_sizes, int n_in,
                              void* d_out, int out_size, void* d_ws, size_t ws_size,
                              hipStream_t stream) {
  const float* x   = (const float*)d_in[0];
  const float* ctx = (const float*)d_in[1];
  const float* Wq  = (const float*)d_in[2];
  const float* Wk  = (const float*)d_in[3];
  const float* Wv  = (const float*)d_in[4];
  const float* Wo  = (const float*)d_in[5];
  const float* bo  = (const float*)d_in[6];

  // ws layout (145.9 MB total; ws>=146MB verified by R1/R2 bit-identical absmax)
  char* ws = (char*)d_ws;
  _Float16* xh   = (_Float16*)(ws + 0);           // [32768][1024] x-f16
  _Float16* Wqt  = (_Float16*)(ws + 67108864);    // [1024][1024]
  _Float16* Wkt  = (_Float16*)(ws + 69206016);    // [1024][768]
  _Float16* Wvt  = (_Float16*)(ws + 70778880);    // [1024][768]
  _Float16* Wot  = (_Float16*)(ws + 72351744);    // [1024][1024]
  _Float16* ctxh = (_Float16*)(ws + 74448896);    // [616][768]
  _Float16* Kg   = (_Float16*)(ws + 75395072);    // [128][77][64]
  _Float16* Vtg  = (_Float16*)(ws + 76656640);    // [128][64][128]
  _Float16* aOut = (_Float16*)(ws + 78774272);    // [32768][1024] attnOut (end 145.9MB)

  k_prep<<<5735, 256, 0, stream>>>(x, ctx, Wq, Wk, Wv, Wo,
                                   xh, ctxh, Wqt, Wkt, Wvt, Wot, Vtg);
  k_kvproj<<<dim3(39, 64), 64, 0, stream>>>(ctxh, Wkt, Wvt, Kg, Vtg);
  // GEMM1 + fused attention: writes attnOut directly (no Qh round trip)
  k_gemm9<0><<<dim3(512), dim3(512), 0, stream>>>(xh, Wqt, (void*)aOut, nullptr,
                                                  Kg, Vtg, 32768, 1024, 1024);
  // GEMM2: O projection + bias -> d_out (f32)
  k_gemm9<1><<<dim3(512), dim3(512), 0, stream>>>(aOut, Wot, d_out, bo,
                                                  nullptr, nullptr, 32768, 1024, 1024);
}